// Round 14
// baseline (420.705 us; speedup 1.0000x reference)
//
#include <hip/hip_runtime.h>
#include <math.h>

#define NN 150000      // nodes (== 16 * 9375)
#define NE 4800000     // edges (without self loops)
#define HD 16          // hidden dim
#define NBUCK 586      // ceil(NN/256) buckets of 256 nodes
#define BSH 8
#define NBLK 256       // partition chunks
#define CHUNK 18750    // NE / NBLK (exact)
#define HCH 9375       // half chunk (staged per phase)
#define NSCAN 150016   // NBUCK * NBLK
#define SCANB 147      // ceil(NSCAN / 1024)

#define NTL(x) __builtin_nontemporal_load(&(x))

// ---- bf16 helpers (bit-level, round-to-nearest-even) ----
__device__ __forceinline__ float bf2f(unsigned short u) {
    return __uint_as_float(((unsigned int)u) << 16);
}
__device__ __forceinline__ unsigned short f2bf(float f) {
    unsigned int x = __float_as_uint(f);
    return (unsigned short)((x + 0x7FFFu + ((x >> 16) & 1u)) >> 16);
}

// ================= phase A: partition edges into 586 dst-buckets =================

__global__ __launch_bounds__(512) void k_part_count(const int* __restrict__ dst,
                                                    int* __restrict__ C) {
    __shared__ int h[NBUCK];
    for (int i = threadIdx.x; i < NBUCK; i += 512) h[i] = 0;
    __syncthreads();
    int base = blockIdx.x * CHUNK;
    for (int i = threadIdx.x; i < CHUNK; i += 512)
        atomicAdd(&h[NTL(dst[base + i]) >> BSH], 1);
    __syncthreads();
    for (int i = threadIdx.x; i < NBUCK; i += 512) C[i * NBLK + blockIdx.x] = h[i];
}

__global__ void k_scanA(int* __restrict__ C, int* __restrict__ psum) {
    __shared__ int s[1024];
    int t = threadIdx.x;
    int i = blockIdx.x * 1024 + t;
    int v = (i < NSCAN) ? C[i] : 0;
    s[t] = v;
    __syncthreads();
    for (int off = 1; off < 1024; off <<= 1) {
        int x = (t >= off) ? s[t - off] : 0;
        __syncthreads();
        s[t] += x;
        __syncthreads();
    }
    if (i < NSCAN) C[i] = s[t] - v;       // local exclusive
    if (t == 1023) psum[blockIdx.x] = s[1023];
}

__global__ void k_scanB(int* __restrict__ psum) {
    __shared__ int s[512];
    int t = threadIdx.x;
    int v = (t < SCANB) ? psum[t] : 0;
    s[t] = v;
    __syncthreads();
    for (int off = 1; off < 512; off <<= 1) {
        int x = (t >= off) ? s[t - off] : 0;
        __syncthreads();
        s[t] += x;
        __syncthreads();
    }
    if (t < SCANB) psum[t] = s[t] - v;    // exclusive
}

__global__ void k_scanC(int* __restrict__ C, const int* __restrict__ psum,
                        int* __restrict__ bstart) {
    int i = blockIdx.x * 1024 + threadIdx.x;
    if (i >= NSCAN) return;
    int v = C[i] + psum[blockIdx.x];
    C[i] = v;
    if ((i & (NBLK - 1)) == 0) bstart[i >> BSH] = v;   // (b, chunk=0) -> bucket base
    if (i == 0) bstart[NBUCK] = NE;
}

// LDS-staged multisplit scatter: per half-chunk, {histogram -> wave scan ->
// bucket-ordered LDS stage -> per-bucket coalesced burst flush}. Output runs are
// written as contiguous bursts (full 64B lines except run boundaries), and nt
// loads keep the streams out of L2 so dirty output lines survive until writeback.
__global__ __launch_bounds__(512) void k_part_scatter(const int* __restrict__ src,
                                                      const int* __restrict__ dst,
                                                      const int* __restrict__ C,
                                                      int* __restrict__ packed) {
    __shared__ int gcur[NBUCK];    // global run cursors
    __shared__ int lcnt[NBUCK];    // per-phase counts
    __shared__ int lofs[NBUCK];    // per-phase exclusive offsets -> fill cursors
    __shared__ int stage[HCH];     // bucket-ordered staged packed values (37.5 KB)
    int tid = threadIdx.x;
    int bid = blockIdx.x;
    int m = ((bid & 7) << 5) | (bid >> 3);   // XCD-aware chunk swizzle, bijective on [0,256)
    for (int i = tid; i < NBUCK; i += 512) gcur[i] = C[i * NBLK + m];
    for (int ph = 0; ph < 2; ++ph) {
        int base = m * CHUNK + ph * HCH;
        for (int i = tid; i < NBUCK; i += 512) lcnt[i] = 0;
        __syncthreads();
        // pass 1: histogram
        for (int i = tid; i < HCH; i += 512)
            atomicAdd(&lcnt[NTL(dst[base + i]) >> BSH], 1);
        __syncthreads();
        // exclusive scan of lcnt -> lofs (wave 0, 64-lane shfl scan)
        if (tid < 64) {
            int run = 0;
            for (int b0 = 0; b0 < NBUCK; b0 += 64) {
                int idx = b0 + tid;
                int c = (idx < NBUCK) ? lcnt[idx] : 0;
                int inc = c;
#pragma unroll
                for (int off = 1; off < 64; off <<= 1) {
                    int y = __shfl_up(inc, off);
                    if (tid >= off) inc += y;
                }
                if (idx < NBUCK) lofs[idx] = run + inc - c;
                run += __shfl(inc, 63);
            }
        }
        __syncthreads();
        // pass 2: scatter into bucket-ordered stage
        for (int i = tid; i < HCH; i += 512) {
            int s = NTL(src[base + i]);
            int d = NTL(dst[base + i]);
            int b = d >> BSH;
            int pos = atomicAdd(&lofs[b], 1);
            stage[pos] = (s << BSH) | (d & 255);
        }
        __syncthreads();
        // flush: each wave takes buckets round-robin, bursts its run to global
        int wv = tid >> 6, ln = tid & 63;
        for (int b = wv; b < NBUCK; b += 8) {
            int c = lcnt[b];
            int ls = lofs[b] - c;     // lofs is now start+count
            int gs = gcur[b];
            for (int k = ln; k < c; k += 64) packed[gs + k] = stage[ls + k];
        }
        __syncthreads();
        for (int i = tid; i < NBUCK; i += 512) gcur[i] += lcnt[i];   // same-thread i: safe
    }
}

// ================= phase B: per-bucket local counting sort =================
__global__ __launch_bounds__(256) void k_bucket_sort(const int* __restrict__ packed,
                                                     const int* __restrict__ bstart,
                                                     int* __restrict__ row_start,
                                                     float* __restrict__ dinv,
                                                     int* __restrict__ ssrc) {
    __shared__ int hist[256];
    __shared__ int fill[256];
    int b = blockIdx.x;
    int t = threadIdx.x;
    int v0 = b << BSH;
    int nv = min(256, NN - v0);
    int e0 = bstart[b], e1 = bstart[b + 1];
    hist[t] = 0;
    __syncthreads();
    for (int e = e0 + t; e < e1; e += 256)
        atomicAdd(&hist[NTL(packed[e]) & 255], 1);
    __syncthreads();
    int cv = hist[t];
    __syncthreads();
    for (int off = 1; off < 256; off <<= 1) {
        int x = (t >= off) ? hist[t - off] : 0;
        __syncthreads();
        hist[t] += x;
        __syncthreads();
    }
    int excl = hist[t] - cv;
    if (t < nv) {
        row_start[v0 + t] = e0 + excl;
        fill[t] = e0 + excl;
        dinv[v0 + t] = rsqrtf((float)cv + 1.0f);   // +1: self loop
    }
    __syncthreads();
    for (int e = e0 + t; e < e1; e += 256) {
        int p = NTL(packed[e]);
        int pos = atomicAdd(&fill[p & 255], 1);
        ssrc[pos] = p >> BSH;
    }
    if (b == 0 && t == 0) row_start[NN] = NE;
}

// ================= layer 1 transform: t = (x @ W_in) * dinv (bf16 out) =================
__global__ __launch_bounds__(256) void k_transform_in(const float* __restrict__ x,
                                                      const float* __restrict__ W,
                                                      const float* __restrict__ dinv,
                                                      unsigned short* __restrict__ t) {
    int gid = blockIdx.x * blockDim.x + threadIdx.x;
    if (gid >= NN * HD) return;
    int v = gid >> 4, j = gid & 15;
    float s = x[v * 3 + 0] * W[j] + x[v * 3 + 1] * W[HD + j] + x[v * 3 + 2] * W[2 * HD + j];
    t[gid] = f2bf(s * dinv[v]);
}

// ============ fused gather + relu + next transform (16 -> 16) ============
// 32 lanes per node, 8 lanes per edge (2 features/lane as one u32 load).
// ssrc stream read nontemporal so the 4.8 MB t-table stays L2-resident.
__global__ __launch_bounds__(512) void k_gather_mid(const int* __restrict__ row_start,
                                                    const int* __restrict__ ssrc,
                                                    const unsigned short* __restrict__ t,
                                                    const float* __restrict__ dinv,
                                                    const float* __restrict__ b,
                                                    const float* __restrict__ W,
                                                    unsigned short* __restrict__ tnext) {
    __shared__ float sW[HD * HD];
    __shared__ float sh[16 * HD];
    int tid = threadIdx.x;
    if (tid < HD * HD) sW[tid] = W[tid];
    int node = tid >> 5;            // 0..15
    int lane = tid & 31;
    int sub  = lane >> 3;           // 0..3: edge slot
    int fl   = lane & 7;            // feature pair: j = 2*fl, 2*fl+1
    int v = blockIdx.x * 16 + node;
    int e0 = row_start[v], e1 = row_start[v + 1];
    float sx = 0.0f, sy = 0.0f;
    int e = e0 + sub;
    for (; e + 4 < e1; e += 8) {    // slots e and e+4 both valid for this sub
        int sA = NTL(ssrc[e]), sB = NTL(ssrc[e + 4]);
        unsigned int wA = *(const unsigned int*)(t + (size_t)sA * HD + 2 * fl);
        unsigned int wB = *(const unsigned int*)(t + (size_t)sB * HD + 2 * fl);
        sx += bf2f((unsigned short)wA) + bf2f((unsigned short)wB);
        sy += bf2f((unsigned short)(wA >> 16)) + bf2f((unsigned short)(wB >> 16));
    }
    for (; e < e1; e += 4) {
        unsigned int w = *(const unsigned int*)(t + (size_t)NTL(ssrc[e]) * HD + 2 * fl);
        sx += bf2f((unsigned short)w);
        sy += bf2f((unsigned short)(w >> 16));
    }
    if (sub == 0) {                 // self loop, counted once
        unsigned int w = *(const unsigned int*)(t + (size_t)v * HD + 2 * fl);
        sx += bf2f((unsigned short)w);
        sy += bf2f((unsigned short)(w >> 16));
    }
    sx += __shfl_xor(sx, 8);  sx += __shfl_xor(sx, 16);
    sy += __shfl_xor(sy, 8);  sy += __shfl_xor(sy, 16);
    if (sub == 0) {
        float di = dinv[v];
        sh[node * HD + 2 * fl]     = fmaxf(sx * di + b[2 * fl], 0.0f);
        sh[node * HD + 2 * fl + 1] = fmaxf(sy * di + b[2 * fl + 1], 0.0f);
    }
    __syncthreads();
    if (tid < 256) {
        int n = tid >> 4, jj = tid & 15;
        int vv = blockIdx.x * 16 + n;
        float o = 0.0f;
#pragma unroll
        for (int k = 0; k < HD; ++k) o += sh[n * HD + k] * sW[k * HD + jj];
        tnext[(size_t)vv * HD + jj] = f2bf(o * dinv[vv]);
    }
}

// ============ fused gather + relu + output dot (16 -> 1) ============
__global__ __launch_bounds__(512) void k_gather_out(const int* __restrict__ row_start,
                                                    const int* __restrict__ ssrc,
                                                    const unsigned short* __restrict__ t,
                                                    const float* __restrict__ dinv,
                                                    const float* __restrict__ b,
                                                    const float* __restrict__ Wout,
                                                    float* __restrict__ t3) {
    int tid = threadIdx.x;
    int node = tid >> 5;
    int lane = tid & 31;
    int sub  = lane >> 3;
    int fl   = lane & 7;
    int v = blockIdx.x * 16 + node;
    int e0 = row_start[v], e1 = row_start[v + 1];
    float sx = 0.0f, sy = 0.0f;
    int e = e0 + sub;
    for (; e + 4 < e1; e += 8) {
        int sA = NTL(ssrc[e]), sB = NTL(ssrc[e + 4]);
        unsigned int wA = *(const unsigned int*)(t + (size_t)sA * HD + 2 * fl);
        unsigned int wB = *(const unsigned int*)(t + (size_t)sB * HD + 2 * fl);
        sx += bf2f((unsigned short)wA) + bf2f((unsigned short)wB);
        sy += bf2f((unsigned short)(wA >> 16)) + bf2f((unsigned short)(wB >> 16));
    }
    for (; e < e1; e += 4) {
        unsigned int w = *(const unsigned int*)(t + (size_t)NTL(ssrc[e]) * HD + 2 * fl);
        sx += bf2f((unsigned short)w);
        sy += bf2f((unsigned short)(w >> 16));
    }
    if (sub == 0) {
        unsigned int w = *(const unsigned int*)(t + (size_t)v * HD + 2 * fl);
        sx += bf2f((unsigned short)w);
        sy += bf2f((unsigned short)(w >> 16));
    }
    sx += __shfl_xor(sx, 8);  sx += __shfl_xor(sx, 16);
    sy += __shfl_xor(sy, 8);  sy += __shfl_xor(sy, 16);
    float di = dinv[v];
    float hx = fmaxf(sx * di + b[2 * fl], 0.0f);
    float hy = fmaxf(sy * di + b[2 * fl + 1], 0.0f);
    float d = hx * Wout[2 * fl] + hy * Wout[2 * fl + 1];
    d += __shfl_xor(d, 1);
    d += __shfl_xor(d, 2);
    d += __shfl_xor(d, 4);
    if (lane == 0) t3[v] = d * di;
}

// ============ final: gather t3 (scalar), bias, sigmoid ============
__global__ __launch_bounds__(256) void k_gather_final(const int* __restrict__ row_start,
                                                      const int* __restrict__ ssrc,
                                                      const float* __restrict__ t3,
                                                      const float* __restrict__ dinv,
                                                      const float* __restrict__ b_out,
                                                      float* __restrict__ out) {
    int tid = threadIdx.x;
    int v = blockIdx.x * 16 + (tid >> 4);
    int l = tid & 15;
    int e0 = row_start[v], e1 = row_start[v + 1];
    float sum = 0.0f;
    for (int e = e0 + l; e < e1; e += 16) sum += t3[NTL(ssrc[e])];
    sum += __shfl_xor(sum, 1);
    sum += __shfl_xor(sum, 2);
    sum += __shfl_xor(sum, 4);
    sum += __shfl_xor(sum, 8);
    if (l == 0) {
        float z = (sum + t3[v]) * dinv[v] + b_out[0];
        out[v] = 1.0f / (1.0f + expf(-z));
    }
}

extern "C" void kernel_launch(void* const* d_in, const int* in_sizes, int n_in,
                              void* d_out, int out_size, void* d_ws, size_t ws_size,
                              hipStream_t stream) {
    const float* x     = (const float*)d_in[0];
    const int*   ei    = (const int*)d_in[1];
    const float* W_in  = (const float*)d_in[2];
    const float* b_in  = (const float*)d_in[3];
    const float* W_mid = (const float*)d_in[4];
    const float* b_mid = (const float*)d_in[5];
    const float* W_out = (const float*)d_in[6];
    const float* b_out = (const float*)d_in[7];
    float* out = (float*)d_out;

    const int* src = ei;
    const int* dst = ei + NE;

    // workspace (~41 MB): tA/tB/t3 alias `packed` (dead after k_bucket_sort)
    char* p = (char*)d_ws;
    int*   C         = (int*)p;      p += sizeof(int) * NSCAN;
    int*   psum      = (int*)p;      p += sizeof(int) * 160;
    int*   bstart    = (int*)p;      p += sizeof(int) * (NBUCK + 2);
    int*   row_start = (int*)p;      p += sizeof(int) * (NN + 1);
    float* dinv      = (float*)p;    p += sizeof(float) * NN;
    int*   ssrc      = (int*)p;      p += sizeof(int) * (size_t)NE;   // live through gathers
    int*   packed    = (int*)p;      p += sizeof(int) * (size_t)NE;   // dead after bucket_sort
    unsigned short* tA = (unsigned short*)packed;                      // alias
    unsigned short* tB = tA + (size_t)NN * HD;                         // alias
    float* t3          = (float*)(tB + (size_t)NN * HD);               // alias

    const int gNH = (NN * HD + 255) / 256;  // 9375
    const int gV  = NN / 16;                // 9375

    // ---- build dst-bucketed CSR via two-level counting sort ----
    k_part_count<<<NBLK, 512, 0, stream>>>(dst, C);
    k_scanA<<<SCANB, 1024, 0, stream>>>(C, psum);
    k_scanB<<<1, 512, 0, stream>>>(psum);
    k_scanC<<<SCANB, 1024, 0, stream>>>(C, psum, bstart);
    k_part_scatter<<<NBLK, 512, 0, stream>>>(src, dst, C, packed);
    k_bucket_sort<<<NBUCK, 256, 0, stream>>>(packed, bstart, row_start, dinv, ssrc);

    // ---- layers ----
    k_transform_in<<<gNH, 256, 0, stream>>>(x, W_in, dinv, tA);
    k_gather_mid<<<gV, 512, 0, stream>>>(row_start, ssrc, tA, dinv, b_in, W_mid, tB);
    k_gather_out<<<gV, 512, 0, stream>>>(row_start, ssrc, tB, dinv, b_mid, W_out, t3);
    k_gather_final<<<gV, 256, 0, stream>>>(row_start, ssrc, t3, dinv, b_out, out);
}

// Round 15
// 349.039 us; speedup vs baseline: 1.2053x; 1.2053x over previous
//
#include <hip/hip_runtime.h>
#include <math.h>

#define NN 150000      // nodes (== 16 * 9375)
#define NE 4800000     // edges (without self loops)
#define HD 16          // hidden dim
#define NBUCK 586      // ceil(NN/256) buckets of 256 nodes
#define BSH 8
#define NBLK 256       // partition chunks
#define CHUNK 18750    // NE / NBLK (exact)
#define HCH 9375       // half chunk (staged per phase)
#define NSCAN 150016   // NBUCK * NBLK
#define SCANB 147      // ceil(NSCAN / 1024)

// ---- bf16 helpers (bit-level, round-to-nearest-even) ----
__device__ __forceinline__ float bf2f(unsigned short u) {
    return __uint_as_float(((unsigned int)u) << 16);
}
__device__ __forceinline__ unsigned short f2bf(float f) {
    unsigned int x = __float_as_uint(f);
    return (unsigned short)((x + 0x7FFFu + ((x >> 16) & 1u)) >> 16);
}

// ================= phase A: partition edges into 586 dst-buckets =================

__global__ __launch_bounds__(512) void k_part_count(const int* __restrict__ dst,
                                                    int* __restrict__ C) {
    __shared__ int h[NBUCK];
    for (int i = threadIdx.x; i < NBUCK; i += 512) h[i] = 0;
    __syncthreads();
    int base = blockIdx.x * CHUNK;
    for (int i = threadIdx.x; i < CHUNK; i += 512)
        atomicAdd(&h[dst[base + i] >> BSH], 1);
    __syncthreads();
    for (int i = threadIdx.x; i < NBUCK; i += 512) C[i * NBLK + blockIdx.x] = h[i];
}

__global__ void k_scanA(int* __restrict__ C, int* __restrict__ psum) {
    __shared__ int s[1024];
    int t = threadIdx.x;
    int i = blockIdx.x * 1024 + t;
    int v = (i < NSCAN) ? C[i] : 0;
    s[t] = v;
    __syncthreads();
    for (int off = 1; off < 1024; off <<= 1) {
        int x = (t >= off) ? s[t - off] : 0;
        __syncthreads();
        s[t] += x;
        __syncthreads();
    }
    if (i < NSCAN) C[i] = s[t] - v;       // local exclusive
    if (t == 1023) psum[blockIdx.x] = s[1023];
}

__global__ void k_scanB(int* __restrict__ psum) {
    __shared__ int s[512];
    int t = threadIdx.x;
    int v = (t < SCANB) ? psum[t] : 0;
    s[t] = v;
    __syncthreads();
    for (int off = 1; off < 512; off <<= 1) {
        int x = (t >= off) ? s[t - off] : 0;
        __syncthreads();
        s[t] += x;
        __syncthreads();
    }
    if (t < SCANB) psum[t] = s[t] - v;    // exclusive
}

__global__ void k_scanC(int* __restrict__ C, const int* __restrict__ psum,
                        int* __restrict__ bstart) {
    int i = blockIdx.x * 1024 + threadIdx.x;
    if (i >= NSCAN) return;
    int v = C[i] + psum[blockIdx.x];
    C[i] = v;
    if ((i & (NBLK - 1)) == 0) bstart[i >> BSH] = v;   // (b, chunk=0) -> bucket base
    if (i == 0) bstart[NBUCK] = NE;
}

// LDS-staged multisplit scatter: per half-chunk, {histogram -> wave scan ->
// bucket-ordered LDS stage -> per-bucket coalesced burst flush}. Output runs are
// written as contiguous bursts (full 64B lines except at run boundaries).
__global__ __launch_bounds__(512) void k_part_scatter(const int* __restrict__ src,
                                                      const int* __restrict__ dst,
                                                      const int* __restrict__ C,
                                                      int* __restrict__ packed) {
    __shared__ int gcur[NBUCK];    // global run cursors
    __shared__ int lcnt[NBUCK];    // per-phase counts
    __shared__ int lofs[NBUCK];    // per-phase exclusive offsets -> fill cursors
    __shared__ int stage[HCH];     // bucket-ordered staged packed values (37.5 KB)
    int tid = threadIdx.x;
    int bid = blockIdx.x;
    int m = ((bid & 7) << 5) | (bid >> 3);   // XCD-aware chunk swizzle, bijective on [0,256)
    for (int i = tid; i < NBUCK; i += 512) gcur[i] = C[i * NBLK + m];
    for (int ph = 0; ph < 2; ++ph) {
        int base = m * CHUNK + ph * HCH;
        for (int i = tid; i < NBUCK; i += 512) lcnt[i] = 0;
        __syncthreads();
        // pass 1: histogram
        for (int i = tid; i < HCH; i += 512)
            atomicAdd(&lcnt[dst[base + i] >> BSH], 1);
        __syncthreads();
        // exclusive scan of lcnt -> lofs (wave 0, 64-lane shfl scan)
        if (tid < 64) {
            int run = 0;
            for (int b0 = 0; b0 < NBUCK; b0 += 64) {
                int idx = b0 + tid;
                int c = (idx < NBUCK) ? lcnt[idx] : 0;
                int inc = c;
#pragma unroll
                for (int off = 1; off < 64; off <<= 1) {
                    int y = __shfl_up(inc, off);
                    if (tid >= off) inc += y;
                }
                if (idx < NBUCK) lofs[idx] = run + inc - c;
                run += __shfl(inc, 63);
            }
        }
        __syncthreads();
        // pass 2: scatter into bucket-ordered stage
        for (int i = tid; i < HCH; i += 512) {
            int s = src[base + i];
            int d = dst[base + i];
            int b = d >> BSH;
            int pos = atomicAdd(&lofs[b], 1);
            stage[pos] = (s << BSH) | (d & 255);
        }
        __syncthreads();
        // flush: each wave takes buckets round-robin, bursts its run to global
        int wv = tid >> 6, ln = tid & 63;
        for (int b = wv; b < NBUCK; b += 8) {
            int c = lcnt[b];
            int ls = lofs[b] - c;     // lofs is now start+count
            int gs = gcur[b];
            for (int k = ln; k < c; k += 64) packed[gs + k] = stage[ls + k];
        }
        __syncthreads();
        for (int i = tid; i < NBUCK; i += 512) gcur[i] += lcnt[i];   // same-thread i: safe
    }
}

// ================= phase B: per-bucket local counting sort =================
__global__ __launch_bounds__(256) void k_bucket_sort(const int* __restrict__ packed,
                                                     const int* __restrict__ bstart,
                                                     int* __restrict__ row_start,
                                                     float* __restrict__ dinv,
                                                     int* __restrict__ ssrc) {
    __shared__ int hist[256];
    __shared__ int fill[256];
    int b = blockIdx.x;
    int t = threadIdx.x;
    int v0 = b << BSH;
    int nv = min(256, NN - v0);
    int e0 = bstart[b], e1 = bstart[b + 1];
    hist[t] = 0;
    __syncthreads();
    for (int e = e0 + t; e < e1; e += 256)
        atomicAdd(&hist[packed[e] & 255], 1);
    __syncthreads();
    int cv = hist[t];
    __syncthreads();
    for (int off = 1; off < 256; off <<= 1) {
        int x = (t >= off) ? hist[t - off] : 0;
        __syncthreads();
        hist[t] += x;
        __syncthreads();
    }
    int excl = hist[t] - cv;
    if (t < nv) {
        row_start[v0 + t] = e0 + excl;
        fill[t] = e0 + excl;
        dinv[v0 + t] = rsqrtf((float)cv + 1.0f);   // +1: self loop
    }
    __syncthreads();
    for (int e = e0 + t; e < e1; e += 256) {
        int p = packed[e];
        int pos = atomicAdd(&fill[p & 255], 1);
        ssrc[pos] = p >> BSH;
    }
    if (b == 0 && t == 0) row_start[NN] = NE;
}

// ================= layer 1 transform: t = (x @ W_in) * dinv (bf16 out) =================
__global__ __launch_bounds__(256) void k_transform_in(const float* __restrict__ x,
                                                      const float* __restrict__ W,
                                                      const float* __restrict__ dinv,
                                                      unsigned short* __restrict__ t) {
    int gid = blockIdx.x * blockDim.x + threadIdx.x;
    if (gid >= NN * HD) return;
    int v = gid >> 4, j = gid & 15;
    float s = x[v * 3 + 0] * W[j] + x[v * 3 + 1] * W[HD + j] + x[v * 3 + 2] * W[2 * HD + j];
    t[gid] = f2bf(s * dinv[v]);
}

// ============ fused gather + relu + next transform (16 -> 16) ============
// 32 lanes per node, 8 lanes per edge (2 features/lane as one u32 load).
__global__ __launch_bounds__(512) void k_gather_mid(const int* __restrict__ row_start,
                                                    const int* __restrict__ ssrc,
                                                    const unsigned short* __restrict__ t,
                                                    const float* __restrict__ dinv,
                                                    const float* __restrict__ b,
                                                    const float* __restrict__ W,
                                                    unsigned short* __restrict__ tnext) {
    __shared__ float sW[HD * HD];
    __shared__ float sh[16 * HD];
    int tid = threadIdx.x;
    if (tid < HD * HD) sW[tid] = W[tid];
    int node = tid >> 5;            // 0..15
    int lane = tid & 31;
    int sub  = lane >> 3;           // 0..3: edge slot
    int fl   = lane & 7;            // feature pair: j = 2*fl, 2*fl+1
    int v = blockIdx.x * 16 + node;
    int e0 = row_start[v], e1 = row_start[v + 1];
    float sx = 0.0f, sy = 0.0f;
    int e = e0 + sub;
    for (; e + 4 < e1; e += 8) {    // slots e and e+4 both valid for this sub
        int sA = ssrc[e], sB = ssrc[e + 4];
        unsigned int wA = *(const unsigned int*)(t + (size_t)sA * HD + 2 * fl);
        unsigned int wB = *(const unsigned int*)(t + (size_t)sB * HD + 2 * fl);
        sx += bf2f((unsigned short)wA) + bf2f((unsigned short)wB);
        sy += bf2f((unsigned short)(wA >> 16)) + bf2f((unsigned short)(wB >> 16));
    }
    for (; e < e1; e += 4) {
        unsigned int w = *(const unsigned int*)(t + (size_t)ssrc[e] * HD + 2 * fl);
        sx += bf2f((unsigned short)w);
        sy += bf2f((unsigned short)(w >> 16));
    }
    if (sub == 0) {                 // self loop, counted once
        unsigned int w = *(const unsigned int*)(t + (size_t)v * HD + 2 * fl);
        sx += bf2f((unsigned short)w);
        sy += bf2f((unsigned short)(w >> 16));
    }
    sx += __shfl_xor(sx, 8);  sx += __shfl_xor(sx, 16);
    sy += __shfl_xor(sy, 8);  sy += __shfl_xor(sy, 16);
    if (sub == 0) {
        float di = dinv[v];
        sh[node * HD + 2 * fl]     = fmaxf(sx * di + b[2 * fl], 0.0f);
        sh[node * HD + 2 * fl + 1] = fmaxf(sy * di + b[2 * fl + 1], 0.0f);
    }
    __syncthreads();
    if (tid < 256) {
        int n = tid >> 4, jj = tid & 15;
        int vv = blockIdx.x * 16 + n;
        float o = 0.0f;
#pragma unroll
        for (int k = 0; k < HD; ++k) o += sh[n * HD + k] * sW[k * HD + jj];
        tnext[(size_t)vv * HD + jj] = f2bf(o * dinv[vv]);
    }
}

// ============ fused gather + relu + output dot (16 -> 1) ============
__global__ __launch_bounds__(512) void k_gather_out(const int* __restrict__ row_start,
                                                    const int* __restrict__ ssrc,
                                                    const unsigned short* __restrict__ t,
                                                    const float* __restrict__ dinv,
                                                    const float* __restrict__ b,
                                                    const float* __restrict__ Wout,
                                                    float* __restrict__ t3) {
    int tid = threadIdx.x;
    int node = tid >> 5;
    int lane = tid & 31;
    int sub  = lane >> 3;
    int fl   = lane & 7;
    int v = blockIdx.x * 16 + node;
    int e0 = row_start[v], e1 = row_start[v + 1];
    float sx = 0.0f, sy = 0.0f;
    int e = e0 + sub;
    for (; e + 4 < e1; e += 8) {
        int sA = ssrc[e], sB = ssrc[e + 4];
        unsigned int wA = *(const unsigned int*)(t + (size_t)sA * HD + 2 * fl);
        unsigned int wB = *(const unsigned int*)(t + (size_t)sB * HD + 2 * fl);
        sx += bf2f((unsigned short)wA) + bf2f((unsigned short)wB);
        sy += bf2f((unsigned short)(wA >> 16)) + bf2f((unsigned short)(wB >> 16));
    }
    for (; e < e1; e += 4) {
        unsigned int w = *(const unsigned int*)(t + (size_t)ssrc[e] * HD + 2 * fl);
        sx += bf2f((unsigned short)w);
        sy += bf2f((unsigned short)(w >> 16));
    }
    if (sub == 0) {
        unsigned int w = *(const unsigned int*)(t + (size_t)v * HD + 2 * fl);
        sx += bf2f((unsigned short)w);
        sy += bf2f((unsigned short)(w >> 16));
    }
    sx += __shfl_xor(sx, 8);  sx += __shfl_xor(sx, 16);
    sy += __shfl_xor(sy, 8);  sy += __shfl_xor(sy, 16);
    float di = dinv[v];
    float hx = fmaxf(sx * di + b[2 * fl], 0.0f);
    float hy = fmaxf(sy * di + b[2 * fl + 1], 0.0f);
    float d = hx * Wout[2 * fl] + hy * Wout[2 * fl + 1];
    d += __shfl_xor(d, 1);
    d += __shfl_xor(d, 2);
    d += __shfl_xor(d, 4);
    if (lane == 0) t3[v] = d * di;
}

// ============ final: gather t3 (scalar), bias, sigmoid ============
__global__ __launch_bounds__(256) void k_gather_final(const int* __restrict__ row_start,
                                                      const int* __restrict__ ssrc,
                                                      const float* __restrict__ t3,
                                                      const float* __restrict__ dinv,
                                                      const float* __restrict__ b_out,
                                                      float* __restrict__ out) {
    int tid = threadIdx.x;
    int v = blockIdx.x * 16 + (tid >> 4);
    int l = tid & 15;
    int e0 = row_start[v], e1 = row_start[v + 1];
    float sum = 0.0f;
    for (int e = e0 + l; e < e1; e += 16) sum += t3[ssrc[e]];
    sum += __shfl_xor(sum, 1);
    sum += __shfl_xor(sum, 2);
    sum += __shfl_xor(sum, 4);
    sum += __shfl_xor(sum, 8);
    if (l == 0) {
        float z = (sum + t3[v]) * dinv[v] + b_out[0];
        out[v] = 1.0f / (1.0f + expf(-z));
    }
}

extern "C" void kernel_launch(void* const* d_in, const int* in_sizes, int n_in,
                              void* d_out, int out_size, void* d_ws, size_t ws_size,
                              hipStream_t stream) {
    const float* x     = (const float*)d_in[0];
    const int*   ei    = (const int*)d_in[1];
    const float* W_in  = (const float*)d_in[2];
    const float* b_in  = (const float*)d_in[3];
    const float* W_mid = (const float*)d_in[4];
    const float* b_mid = (const float*)d_in[5];
    const float* W_out = (const float*)d_in[6];
    const float* b_out = (const float*)d_in[7];
    float* out = (float*)d_out;

    const int* src = ei;
    const int* dst = ei + NE;

    // workspace (~41 MB): tA/tB/t3 alias `packed` (dead after k_bucket_sort)
    char* p = (char*)d_ws;
    int*   C         = (int*)p;      p += sizeof(int) * NSCAN;
    int*   psum      = (int*)p;      p += sizeof(int) * 160;
    int*   bstart    = (int*)p;      p += sizeof(int) * (NBUCK + 2);
    int*   row_start = (int*)p;      p += sizeof(int) * (NN + 1);
    float* dinv      = (float*)p;    p += sizeof(float) * NN;
    int*   ssrc      = (int*)p;      p += sizeof(int) * (size_t)NE;   // live through gathers
    int*   packed    = (int*)p;      p += sizeof(int) * (size_t)NE;   // dead after bucket_sort
    unsigned short* tA = (unsigned short*)packed;                      // alias
    unsigned short* tB = tA + (size_t)NN * HD;                         // alias
    float* t3          = (float*)(tB + (size_t)NN * HD);               // alias

    const int gNH = (NN * HD + 255) / 256;  // 9375
    const int gV  = NN / 16;                // 9375

    // ---- build dst-bucketed CSR via two-level counting sort ----
    k_part_count<<<NBLK, 512, 0, stream>>>(dst, C);
    k_scanA<<<SCANB, 1024, 0, stream>>>(C, psum);
    k_scanB<<<1, 512, 0, stream>>>(psum);
    k_scanC<<<SCANB, 1024, 0, stream>>>(C, psum, bstart);
    k_part_scatter<<<NBLK, 512, 0, stream>>>(src, dst, C, packed);
    k_bucket_sort<<<NBUCK, 256, 0, stream>>>(packed, bstart, row_start, dinv, ssrc);

    // ---- layers ----
    k_transform_in<<<gNH, 256, 0, stream>>>(x, W_in, dinv, tA);
    k_gather_mid<<<gV, 512, 0, stream>>>(row_start, ssrc, tA, dinv, b_in, W_mid, tB);
    k_gather_out<<<gV, 512, 0, stream>>>(row_start, ssrc, tB, dinv, b_mid, W_out, t3);
    k_gather_final<<<gV, 256, 0, stream>>>(row_start, ssrc, t3, dinv, b_out, out);
}

// Round 19
// 314.668 us; speedup vs baseline: 1.3370x; 1.1092x over previous
//
#include <hip/hip_runtime.h>
#include <math.h>

#define NN 150000      // nodes (== 16 * 9375)
#define NE 4800000     // edges (without self loops)
#define HD 16          // hidden dim
#define NBUCK 586      // ceil(NN/256) buckets of 256 nodes
#define BSH 8
#define NCH 512        // partition chunks (one per scatter block)
#define HCH 9375       // edges per chunk (NE / NCH exact)
#define NSCAN2 300032  // NBUCK * NCH
#define SCANB2 293     // NSCAN2 / 1024 (exact)

// ---- bf16 helpers (bit-level, round-to-nearest-even) ----
__device__ __forceinline__ float bf2f(unsigned short u) {
    return __uint_as_float(((unsigned int)u) << 16);
}
__device__ __forceinline__ unsigned short f2bf(float f) {
    unsigned int x = __float_as_uint(f);
    return (unsigned short)((x + 0x7FFFu + ((x >> 16) & 1u)) >> 16);
}

// ================= phase A: partition edges into 586 dst-buckets =================

// per half-chunk bucket histogram -> Craw[b * NCH + chunk]  (raw counts kept!)
__global__ __launch_bounds__(512) void k_part_count(const int* __restrict__ dst,
                                                    int* __restrict__ Craw) {
    __shared__ int h[NBUCK];
    for (int i = threadIdx.x; i < NBUCK; i += 512) h[i] = 0;
    __syncthreads();
    int base = blockIdx.x * HCH;
    for (int i = threadIdx.x; i < HCH; i += 512)
        atomicAdd(&h[dst[base + i] >> BSH], 1);
    __syncthreads();
    for (int i = threadIdx.x; i < NBUCK; i += 512) Craw[i * NCH + blockIdx.x] = h[i];
}

__global__ void k_scanA(const int* __restrict__ Craw, int* __restrict__ Cscan,
                        int* __restrict__ psum) {
    __shared__ int s[1024];
    int t = threadIdx.x;
    int i = blockIdx.x * 1024 + t;
    int v = Craw[i];
    s[t] = v;
    __syncthreads();
    for (int off = 1; off < 1024; off <<= 1) {
        int x = (t >= off) ? s[t - off] : 0;
        __syncthreads();
        s[t] += x;
        __syncthreads();
    }
    Cscan[i] = s[t] - v;                  // local exclusive
    if (t == 1023) psum[blockIdx.x] = s[1023];
}

__global__ void k_scanB(int* __restrict__ psum) {
    __shared__ int s[512];
    int t = threadIdx.x;
    int v = (t < SCANB2) ? psum[t] : 0;
    s[t] = v;
    __syncthreads();
    for (int off = 1; off < 512; off <<= 1) {
        int x = (t >= off) ? s[t - off] : 0;
        __syncthreads();
        s[t] += x;
        __syncthreads();
    }
    if (t < SCANB2) psum[t] = s[t] - v;   // exclusive
}

__global__ void k_scanC(int* __restrict__ Cscan, const int* __restrict__ psum,
                        int* __restrict__ bstart) {
    int i = blockIdx.x * 1024 + threadIdx.x;
    int v = Cscan[i] + psum[blockIdx.x];
    Cscan[i] = v;
    if ((i & (NCH - 1)) == 0) bstart[i >> 9] = v;   // (b, chunk=0) -> bucket base
    if (i == 0) bstart[NBUCK] = NE;
}

// LDS-staged multisplit scatter, one half-chunk per block (512 blocks, 2/CU).
// lcnt comes from Craw (no re-histogram); stage is bucket-ordered; flush bursts
// each bucket run contiguously (16-lane groups since runs are ~16 edges).
__global__ __launch_bounds__(512) void k_part_scatter(const int* __restrict__ src,
                                                      const int* __restrict__ dst,
                                                      const int* __restrict__ Craw,
                                                      const int* __restrict__ Cscan,
                                                      int* __restrict__ packed) {
    __shared__ int lcnt[NBUCK];    // this chunk's per-bucket counts (from Craw)
    __shared__ int lofs[NBUCK];    // exclusive scan -> fill cursors
    __shared__ int stage[HCH];     // bucket-ordered staged packed values (37.5 KB)
    int tid = threadIdx.x;
    int bid = blockIdx.x;
    int m = ((bid & 7) << 6) | (bid >> 3);   // XCD-aware swizzle, bijective on [0,512)
    for (int i = tid; i < NBUCK; i += 512) lcnt[i] = Craw[i * NCH + m];
    __syncthreads();
    // exclusive scan of lcnt -> lofs (wave 0, 64-lane shfl scan)
    if (tid < 64) {
        int run = 0;
        for (int b0 = 0; b0 < NBUCK; b0 += 64) {
            int idx = b0 + tid;
            int c = (idx < NBUCK) ? lcnt[idx] : 0;
            int inc = c;
#pragma unroll
            for (int off = 1; off < 64; off <<= 1) {
                int y = __shfl_up(inc, off);
                if (tid >= off) inc += y;
            }
            if (idx < NBUCK) lofs[idx] = run + inc - c;
            run += __shfl(inc, 63);
        }
    }
    __syncthreads();
    // scatter into bucket-ordered stage
    int base = m * HCH;
    for (int i = tid; i < HCH; i += 512) {
        int s = src[base + i];
        int d = dst[base + i];
        int b = d >> BSH;
        int pos = atomicAdd(&lofs[b], 1);
        stage[pos] = (s << BSH) | (d & 255);
    }
    __syncthreads();
    // flush: 16-lane groups take buckets round-robin, burst runs to global
    int grp = tid >> 4, ln = tid & 15;     // 32 groups
    for (int b = grp; b < NBUCK; b += 32) {
        int c = lcnt[b];
        int ls = lofs[b] - c;              // lofs is now start+count
        int gs = Cscan[b * NCH + m];
        for (int k = ln; k < c; k += 16) packed[gs + k] = stage[ls + k];
    }
}

// ================= phase B: per-bucket local counting sort =================
__global__ __launch_bounds__(512) void k_bucket_sort(const int* __restrict__ packed,
                                                     const int* __restrict__ bstart,
                                                     int* __restrict__ row_start,
                                                     float* __restrict__ dinv,
                                                     int* __restrict__ ssrc) {
    __shared__ int hist[256];
    __shared__ int fill[256];
    int b = blockIdx.x;
    int t = threadIdx.x;
    int v0 = b << BSH;
    int nv = min(256, NN - v0);
    int e0 = bstart[b], e1 = bstart[b + 1];
    if (t < 256) hist[t] = 0;
    __syncthreads();
    for (int e = e0 + t; e < e1; e += 512)
        atomicAdd(&hist[packed[e] & 255], 1);
    __syncthreads();
    int cv = (t < 256) ? hist[t] : 0;
    __syncthreads();
    for (int off = 1; off < 256; off <<= 1) {
        int x = (t >= off && t < 256) ? hist[t - off] : 0;
        __syncthreads();
        if (t < 256) hist[t] += x;
        __syncthreads();
    }
    if (t < nv) {
        int excl = hist[t] - cv;
        row_start[v0 + t] = e0 + excl;
        fill[t] = e0 + excl;
        dinv[v0 + t] = rsqrtf((float)cv + 1.0f);   // +1: self loop
    }
    __syncthreads();
    for (int e = e0 + t; e < e1; e += 512) {
        int p = packed[e];
        int pos = atomicAdd(&fill[p & 255], 1);
        ssrc[pos] = p >> BSH;
    }
    if (b == 0 && t == 0) row_start[NN] = NE;
}

// ================= layer 1 transform: t = (x @ W_in) * dinv (bf16 out) =================
__global__ __launch_bounds__(256) void k_transform_in(const float* __restrict__ x,
                                                      const float* __restrict__ W,
                                                      const float* __restrict__ dinv,
                                                      unsigned short* __restrict__ t) {
    int gid = blockIdx.x * blockDim.x + threadIdx.x;
    if (gid >= NN * HD) return;
    int v = gid >> 4, j = gid & 15;
    float s = x[v * 3 + 0] * W[j] + x[v * 3 + 1] * W[HD + j] + x[v * 3 + 2] * W[2 * HD + j];
    t[gid] = f2bf(s * dinv[v]);
}

// ============ fused gather + relu + next transform (16 -> 16) ============
// 32 lanes per node, 8 lanes per edge (2 features/lane as one u32 load).
__global__ __launch_bounds__(512) void k_gather_mid(const int* __restrict__ row_start,
                                                    const int* __restrict__ ssrc,
                                                    const unsigned short* __restrict__ t,
                                                    const float* __restrict__ dinv,
                                                    const float* __restrict__ b,
                                                    const float* __restrict__ W,
                                                    unsigned short* __restrict__ tnext) {
    __shared__ float sW[HD * HD];
    __shared__ float sh[16 * HD];
    int tid = threadIdx.x;
    if (tid < HD * HD) sW[tid] = W[tid];
    int node = tid >> 5;            // 0..15
    int lane = tid & 31;
    int sub  = lane >> 3;           // 0..3: edge slot
    int fl   = lane & 7;            // feature pair: j = 2*fl, 2*fl+1
    int v = blockIdx.x * 16 + node;
    int e0 = row_start[v], e1 = row_start[v + 1];
    float sx = 0.0f, sy = 0.0f;
    int e = e0 + sub;
    for (; e + 4 < e1; e += 8) {    // slots e and e+4 both valid for this sub
        int sA = ssrc[e], sB = ssrc[e + 4];
        unsigned int wA = *(const unsigned int*)(t + (size_t)sA * HD + 2 * fl);
        unsigned int wB = *(const unsigned int*)(t + (size_t)sB * HD + 2 * fl);
        sx += bf2f((unsigned short)wA) + bf2f((unsigned short)wB);
        sy += bf2f((unsigned short)(wA >> 16)) + bf2f((unsigned short)(wB >> 16));
    }
    for (; e < e1; e += 4) {
        unsigned int w = *(const unsigned int*)(t + (size_t)ssrc[e] * HD + 2 * fl);
        sx += bf2f((unsigned short)w);
        sy += bf2f((unsigned short)(w >> 16));
    }
    if (sub == 0) {                 // self loop, counted once
        unsigned int w = *(const unsigned int*)(t + (size_t)v * HD + 2 * fl);
        sx += bf2f((unsigned short)w);
        sy += bf2f((unsigned short)(w >> 16));
    }
    sx += __shfl_xor(sx, 8);  sx += __shfl_xor(sx, 16);
    sy += __shfl_xor(sy, 8);  sy += __shfl_xor(sy, 16);
    if (sub == 0) {
        float di = dinv[v];
        sh[node * HD + 2 * fl]     = fmaxf(sx * di + b[2 * fl], 0.0f);
        sh[node * HD + 2 * fl + 1] = fmaxf(sy * di + b[2 * fl + 1], 0.0f);
    }
    __syncthreads();
    if (tid < 256) {
        int n = tid >> 4, jj = tid & 15;
        int vv = blockIdx.x * 16 + n;
        float o = 0.0f;
#pragma unroll
        for (int k = 0; k < HD; ++k) o += sh[n * HD + k] * sW[k * HD + jj];
        tnext[(size_t)vv * HD + jj] = f2bf(o * dinv[vv]);
    }
}

// ============ fused gather + relu + output dot (16 -> 1) ============
__global__ __launch_bounds__(512) void k_gather_out(const int* __restrict__ row_start,
                                                    const int* __restrict__ ssrc,
                                                    const unsigned short* __restrict__ t,
                                                    const float* __restrict__ dinv,
                                                    const float* __restrict__ b,
                                                    const float* __restrict__ Wout,
                                                    float* __restrict__ t3) {
    int tid = threadIdx.x;
    int node = tid >> 5;
    int lane = tid & 31;
    int sub  = lane >> 3;
    int fl   = lane & 7;
    int v = blockIdx.x * 16 + node;
    int e0 = row_start[v], e1 = row_start[v + 1];
    float sx = 0.0f, sy = 0.0f;
    int e = e0 + sub;
    for (; e + 4 < e1; e += 8) {
        int sA = ssrc[e], sB = ssrc[e + 4];
        unsigned int wA = *(const unsigned int*)(t + (size_t)sA * HD + 2 * fl);
        unsigned int wB = *(const unsigned int*)(t + (size_t)sB * HD + 2 * fl);
        sx += bf2f((unsigned short)wA) + bf2f((unsigned short)wB);
        sy += bf2f((unsigned short)(wA >> 16)) + bf2f((unsigned short)(wB >> 16));
    }
    for (; e < e1; e += 4) {
        unsigned int w = *(const unsigned int*)(t + (size_t)ssrc[e] * HD + 2 * fl);
        sx += bf2f((unsigned short)w);
        sy += bf2f((unsigned short)(w >> 16));
    }
    if (sub == 0) {
        unsigned int w = *(const unsigned int*)(t + (size_t)v * HD + 2 * fl);
        sx += bf2f((unsigned short)w);
        sy += bf2f((unsigned short)(w >> 16));
    }
    sx += __shfl_xor(sx, 8);  sx += __shfl_xor(sx, 16);
    sy += __shfl_xor(sy, 8);  sy += __shfl_xor(sy, 16);
    float di = dinv[v];
    float hx = fmaxf(sx * di + b[2 * fl], 0.0f);
    float hy = fmaxf(sy * di + b[2 * fl + 1], 0.0f);
    float d = hx * Wout[2 * fl] + hy * Wout[2 * fl + 1];
    d += __shfl_xor(d, 1);
    d += __shfl_xor(d, 2);
    d += __shfl_xor(d, 4);
    if (lane == 0) t3[v] = d * di;
}

// ============ final: gather t3 (scalar), bias, sigmoid ============
__global__ __launch_bounds__(256) void k_gather_final(const int* __restrict__ row_start,
                                                      const int* __restrict__ ssrc,
                                                      const float* __restrict__ t3,
                                                      const float* __restrict__ dinv,
                                                      const float* __restrict__ b_out,
                                                      float* __restrict__ out) {
    int tid = threadIdx.x;
    int v = blockIdx.x * 16 + (tid >> 4);
    int l = tid & 15;
    int e0 = row_start[v], e1 = row_start[v + 1];
    float sum = 0.0f;
    for (int e = e0 + l; e < e1; e += 16) sum += t3[ssrc[e]];
    sum += __shfl_xor(sum, 1);
    sum += __shfl_xor(sum, 2);
    sum += __shfl_xor(sum, 4);
    sum += __shfl_xor(sum, 8);
    if (l == 0) {
        float z = (sum + t3[v]) * dinv[v] + b_out[0];
        out[v] = 1.0f / (1.0f + expf(-z));
    }
}

extern "C" void kernel_launch(void* const* d_in, const int* in_sizes, int n_in,
                              void* d_out, int out_size, void* d_ws, size_t ws_size,
                              hipStream_t stream) {
    const float* x     = (const float*)d_in[0];
    const int*   ei    = (const int*)d_in[1];
    const float* W_in  = (const float*)d_in[2];
    const float* b_in  = (const float*)d_in[3];
    const float* W_mid = (const float*)d_in[4];
    const float* b_mid = (const float*)d_in[5];
    const float* W_out = (const float*)d_in[6];
    const float* b_out = (const float*)d_in[7];
    float* out = (float*)d_out;

    const int* src = ei;
    const int* dst = ei + NE;

    // workspace (~43 MB): tA/tB/t3 alias `packed` (dead after k_bucket_sort)
    char* p = (char*)d_ws;
    int*   Craw      = (int*)p;      p += sizeof(int) * NSCAN2;       // 1.2 MB
    int*   Cscan     = (int*)p;      p += sizeof(int) * NSCAN2;       // 1.2 MB
    int*   psum      = (int*)p;      p += sizeof(int) * 512;
    int*   bstart    = (int*)p;      p += sizeof(int) * (NBUCK + 2);
    int*   row_start = (int*)p;      p += sizeof(int) * (NN + 1);
    float* dinv      = (float*)p;    p += sizeof(float) * NN;
    int*   ssrc      = (int*)p;      p += sizeof(int) * (size_t)NE;   // live through gathers
    int*   packed    = (int*)p;      p += sizeof(int) * (size_t)NE;   // dead after bucket_sort
    unsigned short* tA = (unsigned short*)packed;                      // alias
    unsigned short* tB = tA + (size_t)NN * HD;                         // alias
    float* t3          = (float*)(tB + (size_t)NN * HD);               // alias

    const int gNH = (NN * HD + 255) / 256;  // 9375
    const int gV  = NN / 16;                // 9375

    // ---- build dst-bucketed CSR via two-level counting sort ----
    k_part_count<<<NCH, 512, 0, stream>>>(dst, Craw);
    k_scanA<<<SCANB2, 1024, 0, stream>>>(Craw, Cscan, psum);
    k_scanB<<<1, 512, 0, stream>>>(psum);
    k_scanC<<<SCANB2, 1024, 0, stream>>>(Cscan, psum, bstart);
    k_part_scatter<<<NCH, 512, 0, stream>>>(src, dst, Craw, Cscan, packed);
    k_bucket_sort<<<NBUCK, 512, 0, stream>>>(packed, bstart, row_start, dinv, ssrc);

    // ---- layers ----
    k_transform_in<<<gNH, 256, 0, stream>>>(x, W_in, dinv, tA);
    k_gather_mid<<<gV, 512, 0, stream>>>(row_start, ssrc, tA, dinv, b_in, W_mid, tB);
    k_gather_out<<<gV, 512, 0, stream>>>(row_start, ssrc, tB, dinv, b_mid, W_out, t3);
    k_gather_final<<<gV, 256, 0, stream>>>(row_start, ssrc, t3, dinv, b_out, out);
}